// Round 1
// baseline (104.126 us; speedup 1.0000x reference)
//
#include <hip/hip_runtime.h>

#define TASKS 16
#define DIM 1024
#define HID 128
#define NCLS 10
#define NB 65536
#define BM 128
#define NTILE_MAX (NB / BM + TASKS) // 528

typedef __attribute__((ext_vector_type(8))) short bf16x8;
typedef __attribute__((ext_vector_type(4))) float f32x4;

__device__ __forceinline__ short f2bf(float f) {
    union { float f; unsigned u; } v; v.f = f;
    unsigned r = v.u + 0x7FFFu + ((v.u >> 16) & 1u);  // round-nearest-even
    return (short)(r >> 16);
}

// ---- pass 1: histogram of task ids (LDS-aggregated) ----
__global__ __launch_bounds__(256) void k_hist(const int* __restrict__ tid_arr,
                                              int* __restrict__ cnt) {
    __shared__ int l[TASKS];
    int tx = threadIdx.x;
    if (tx < TASKS) l[tx] = 0;
    __syncthreads();
    int t = tid_arr[blockIdx.x * 256 + tx];
    atomicAdd(&l[t], 1);
    __syncthreads();
    if (tx < TASKS) atomicAdd(&cnt[tx], l[tx]);
}

// ---- pass 2: tiny serial scan: offsets, tile table, cursors ----
__global__ void k_scan(int* __restrict__ ws) {
    if (threadIdx.x == 0 && blockIdx.x == 0) {
        int* cnt = ws; int* off = ws + 16; int* tb = ws + 33; int* cur = ws + 50;
        int ro = 0, rt = 0;
        for (int t = 0; t < TASKS; ++t) {
            off[t] = ro; cur[t] = ro; tb[t] = rt;
            ro += cnt[t]; rt += (cnt[t] + BM - 1) / BM;
        }
        off[TASKS] = ro; tb[TASKS] = rt;
    }
}

// ---- pass 3: scatter row indices grouped by task ----
// Order within a task is nondeterministic, but each row's output value and
// location depend only on its own data -> output is deterministic.
__global__ __launch_bounds__(256) void k_scatter(const int* __restrict__ tid_arr,
                                                 int* __restrict__ ws) {
    __shared__ int l[TASKS], base[TASKS];
    int* cur = ws + 50;
    int* rowIdx = ws + 256;
    int tx = threadIdx.x;
    if (tx < TASKS) l[tx] = 0;
    __syncthreads();
    int i = blockIdx.x * 256 + tx;
    int t = tid_arr[i];
    int rank = atomicAdd(&l[t], 1);
    __syncthreads();
    if (tx < TASKS) base[tx] = atomicAdd(&cur[tx], l[tx]);
    __syncthreads();
    rowIdx[base[t] + rank] = i;
}

// ---- pass 4: fused grouped GEMM: relu(x*W1[t]+b1[t])*W2[t]+b2[t] ----
// One 128-row tile per WG, 4 waves, BK=32 double-buffered bf16 LDS staging.
__global__ __launch_bounds__(256, 3) void k_main(
    const float* __restrict__ x, const float* __restrict__ W1,
    const float* __restrict__ b1, const float* __restrict__ W2,
    const float* __restrict__ b2, const int* __restrict__ ws,
    float* __restrict__ out)
{
    // stage:    alds [2][128][40] shorts (0..10240), blds [2][128][40] (10240..20480)
    // epilogue: hlds [128][136] shorts (0..17408), w2t [16][136] (17408..19584)
    __shared__ short smem[20480];
    __shared__ int ridx[BM];
    short* alds = smem;
    short* blds = smem + 10240;
    short* hlds = smem;
    short* w2t  = smem + 17408;

    const int* cnt = ws; const int* off = ws + 16; const int* tb = ws + 33;
    const int* rowIdx = ws + 256;

    const int w = blockIdx.x;
    if (w >= tb[TASKS]) return;
    int t = 0;
    #pragma unroll
    for (int i = 1; i < TASKS; ++i) if (w >= tb[i]) t = i;
    const int tileInT = w - tb[t];
    const int gstart = off[t] + tileInT * BM;
    int m = cnt[t] - tileInT * BM; if (m > BM) m = BM;

    const int tid = threadIdx.x;
    if (tid < BM) {
        int rr = tid < m ? tid : (m - 1);   // clamp: partial tiles duplicate last row
        ridx[tid] = rowIdx[gstart + rr];
    }
    __syncthreads();

    // A staging: 2 threads per row, 16 consecutive f32 each (coalesced within row)
    const int ar = tid >> 1;
    const int aq = tid & 1;
    const float* xrow = x + (size_t)ridx[ar] * DIM + aq * 16;
    // B staging: lane-coalesced scalar loads along H give a free k-transpose:
    // thread owns one h column, 16 k values (stride H)
    const int bh = tid & 127;
    const int bq = tid >> 7;
    const float* bbase = W1 + (size_t)t * DIM * HID + bq * 16 * HID + bh;

    const int lane = tid & 63, wv = tid >> 6;
    const int lg = lane >> 4, lr = lane & 15;

    float4 av0, av1, av2, av3;
    float bx[16];
    f32x4 acc[2][8] = {};

    auto LOADA = [&](int kt) {
        const float4* p = (const float4*)(xrow + kt * 32);
        av0 = p[0]; av1 = p[1]; av2 = p[2]; av3 = p[3];
    };
    auto LOADB = [&](int kt) {
        const float* bp = bbase + (size_t)kt * 32 * HID;
        #pragma unroll
        for (int e = 0; e < 16; ++e) bx[e] = bp[e * HID];
    };
    auto STORE_STAGE = [&](int buf) {
        bf16x8 s0, s1;
        s0[0]=f2bf(av0.x); s0[1]=f2bf(av0.y); s0[2]=f2bf(av0.z); s0[3]=f2bf(av0.w);
        s0[4]=f2bf(av1.x); s0[5]=f2bf(av1.y); s0[6]=f2bf(av1.z); s0[7]=f2bf(av1.w);
        s1[0]=f2bf(av2.x); s1[1]=f2bf(av2.y); s1[2]=f2bf(av2.z); s1[3]=f2bf(av2.w);
        s1[4]=f2bf(av3.x); s1[5]=f2bf(av3.y); s1[6]=f2bf(av3.z); s1[7]=f2bf(av3.w);
        short* ap = &alds[(buf * 128 + ar) * 40 + aq * 16];
        *(bf16x8*)ap = s0;
        *(bf16x8*)(ap + 8) = s1;
        bf16x8 t0, t1;
        #pragma unroll
        for (int e = 0; e < 8; ++e) { t0[e] = f2bf(bx[e]); t1[e] = f2bf(bx[e + 8]); }
        short* bpp = &blds[(buf * 128 + bh) * 40 + bq * 16];
        *(bf16x8*)bpp = t0;
        *(bf16x8*)(bpp + 8) = t1;
    };
    auto COMPUTE = [&](int buf) {
        bf16x8 af[2];
        #pragma unroll
        for (int rf = 0; rf < 2; ++rf)
            af[rf] = *(const bf16x8*)&alds[(buf * 128 + wv * 32 + rf * 16 + lr) * 40 + 8 * lg];
        #pragma unroll
        for (int cf = 0; cf < 8; ++cf) {
            bf16x8 bv = *(const bf16x8*)&blds[(buf * 128 + cf * 16 + lr) * 40 + 8 * lg];
            #pragma unroll
            for (int rf = 0; rf < 2; ++rf)
                acc[rf][cf] = __builtin_amdgcn_mfma_f32_16x16x32_bf16(af[rf], bv, acc[rf][cf], 0, 0, 0);
        }
    };

    LOADA(0); LOADB(0); STORE_STAGE(0);
    __syncthreads();
    #pragma unroll 2
    for (int kt = 0; kt < 32; ++kt) {
        if (kt < 31) { LOADA(kt + 1); LOADB(kt + 1); }   // issue loads, hide under MFMA
        COMPUTE(kt & 1);
        if (kt < 31) {
            __syncthreads();
            STORE_STAGE((kt + 1) & 1);
            __syncthreads();
        }
    }
    __syncthreads();   // smem reuse: stage buffers -> h tile

    // epilogue: bias + relu, h -> LDS bf16 (C/D layout: col=lane&15, row=4*(lane>>4)+q)
    #pragma unroll
    for (int cf = 0; cf < 8; ++cf) {
        const int col = cf * 16 + lr;
        const float bv = b1[t * HID + col];
        #pragma unroll
        for (int rf = 0; rf < 2; ++rf) {
            #pragma unroll
            for (int qq = 0; qq < 4; ++qq) {
                const int row = wv * 32 + rf * 16 + lg * 4 + qq;
                float hv = acc[rf][cf][qq] + bv;
                hv = hv > 0.f ? hv : 0.f;
                hlds[row * 136 + col] = f2bf(hv);
            }
        }
    }
    // stage W2^T (N padded 10 -> 16 with zeros)
    for (int idx = tid; idx < 16 * HID; idx += 256) {
        const int c = idx >> 7, hh = idx & 127;
        float v = (c < NCLS) ? W2[((size_t)t * HID + hh) * NCLS + c] : 0.f;
        w2t[c * 136 + hh] = f2bf(v);
    }
    __syncthreads();

    // tiny second GEMM: [128 x 128] * [128 x 16]
    f32x4 acc2[2] = {};
    #pragma unroll
    for (int ks = 0; ks < 4; ++ks) {
        bf16x8 bv = *(const bf16x8*)&w2t[lr * 136 + ks * 32 + 8 * lg];
        #pragma unroll
        for (int rf = 0; rf < 2; ++rf) {
            bf16x8 av = *(const bf16x8*)&hlds[(wv * 32 + rf * 16 + lr) * 136 + ks * 32 + 8 * lg];
            acc2[rf] = __builtin_amdgcn_mfma_f32_16x16x32_bf16(av, bv, acc2[rf], 0, 0, 0);
        }
    }
    if (lr < NCLS) {
        const float b2v = b2[t * NCLS + lr];
        #pragma unroll
        for (int rf = 0; rf < 2; ++rf) {
            #pragma unroll
            for (int qq = 0; qq < 4; ++qq) {
                const int row = wv * 32 + rf * 16 + lg * 4 + qq;
                if (row < m) out[(size_t)ridx[row] * NCLS + lr] = acc2[rf][qq] + b2v;
            }
        }
    }
}

extern "C" void kernel_launch(void* const* d_in, const int* in_sizes, int n_in,
                              void* d_out, int out_size, void* d_ws, size_t ws_size,
                              hipStream_t stream) {
    (void)in_sizes; (void)n_in; (void)out_size; (void)ws_size;
    const float* x       = (const float*)d_in[0];
    const int*   task_id = (const int*)d_in[1];
    const float* W1      = (const float*)d_in[2];
    const float* b1      = (const float*)d_in[3];
    const float* W2      = (const float*)d_in[4];
    const float* b2      = (const float*)d_in[5];
    float* out = (float*)d_out;
    int* ws = (int*)d_ws;
    // ws layout (ints): [0,16) cnt | [16,33) off | [33,50) tile-prefix | [50,66) cursors | [256,256+NB) rowIdx
    hipMemsetAsync(ws, 0, 64, stream);                       // zero cnt[16]
    k_hist<<<NB / 256, 256, 0, stream>>>(task_id, ws);
    k_scan<<<1, 64, 0, stream>>>(ws);
    k_scatter<<<NB / 256, 256, 0, stream>>>(task_id, ws);
    k_main<<<NTILE_MAX, 256, 0, stream>>>(x, W1, b1, W2, b2, ws, out);
}